// Round 1
// baseline (961.802 us; speedup 1.0000x reference)
//
#include <hip/hip_runtime.h>
#include <math.h>

#define I_N 96
#define C_N 96
#define R_N 36
#define W_N 48
#define D_N 256
#define LAM_SM 9.0f
#define LAM_LSE 6.0f
#define MARGIN_F 0.2f

#define SR_STRIDE 260           // 256 + 4 pad (keeps 16B alignment, breaks bank aliasing)
#define SA_STRIDE 37

#define SR_OFF 0
#define SI_OFF (48 * SR_STRIDE)                  // 12480
#define SA_OFF (SI_OFF + 36 * SR_STRIDE)         // 21840
#define AUX_OFF (SA_OFF + 48 * SA_STRIDE)        // 23616
#define LDS_FLOATS (AUX_OFF + 128)               // 23744 floats = 94976 B

__device__ __forceinline__ float dot4(float4 a, float4 b) {
    return a.x * b.x + a.y * b.y + a.z * b.z + a.w * b.w;
}

__global__ __launch_bounds__(256) void xattn_pair_kernel(
    const float* __restrict__ images, const float* __restrict__ recipes,
    const int* __restrict__ cap_lens, float* __restrict__ scores)
{
    __shared__ float lds[LDS_FLOATS];
    float* sR = lds + SR_OFF;   // [48][260]
    float* sI = lds + SI_OFF;   // [36][260]
    float* sA = lds + SA_OFF;   // [48][37]  attn / aw
    float* numA = lds + AUX_OFF;        // [36]
    float* n2A  = lds + AUX_OFF + 40;   // [36]
    float* n1A  = lds + AUX_OFF + 80;   // [36]

    const int t = threadIdx.x;
    const int bid = blockIdx.x;
    const int c = bid % C_N;
    const int i = bid / C_N;
    const int L = cap_lens[c];

    // ---- Stage recipes[c] and images[i] into LDS (float4) ----
    {
        const float4* src = (const float4*)(recipes + (size_t)c * W_N * D_N);
        #pragma unroll
        for (int j = 0; j < 12; ++j) {           // 48*256/4 = 3072 float4 / 256 thr
            int k = t + 256 * j;
            int w = k >> 6;
            int d4 = k & 63;
            *(float4*)(sR + w * SR_STRIDE + 4 * d4) = src[k];
        }
        const float4* srcI = (const float4*)(images + (size_t)i * R_N * D_N);
        #pragma unroll
        for (int j = 0; j < 9; ++j) {            // 36*256/4 = 2304 float4
            int k = t + 256 * j;
            int r = k >> 6;
            int d4 = k & 63;
            *(float4*)(sI + r * SR_STRIDE + 4 * d4) = srcI[k];
        }
    }
    __syncthreads();

    // ---- Phase B: attn[w][r] = leaky_relu(recipes[w] . images[r]) ----
    // 16x16 thread grid, each thread a 3x3 (w,r) tile; r padded 36->48 (clamped, not stored)
    {
        const int tw = t >> 4;
        const int tr = t & 15;
        const int w0 = tw * 3;
        const int r0 = tr * 3;
        const int rr0 = (r0     < R_N) ? r0     : R_N - 1;
        const int rr1 = (r0 + 1 < R_N) ? r0 + 1 : R_N - 1;
        const int rr2 = (r0 + 2 < R_N) ? r0 + 2 : R_N - 1;
        const float* Rp = sR + w0 * SR_STRIDE;
        const float* I0 = sI + rr0 * SR_STRIDE;
        const float* I1 = sI + rr1 * SR_STRIDE;
        const float* I2 = sI + rr2 * SR_STRIDE;
        float acc00 = 0.f, acc01 = 0.f, acc02 = 0.f;
        float acc10 = 0.f, acc11 = 0.f, acc12 = 0.f;
        float acc20 = 0.f, acc21 = 0.f, acc22 = 0.f;
        #pragma unroll 4
        for (int d = 0; d < D_N; d += 4) {
            float4 a0 = *(const float4*)(Rp + d);
            float4 a1 = *(const float4*)(Rp + SR_STRIDE + d);
            float4 a2 = *(const float4*)(Rp + 2 * SR_STRIDE + d);
            float4 b0 = *(const float4*)(I0 + d);
            float4 b1 = *(const float4*)(I1 + d);
            float4 b2 = *(const float4*)(I2 + d);
            acc00 += dot4(a0, b0); acc01 += dot4(a0, b1); acc02 += dot4(a0, b2);
            acc10 += dot4(a1, b0); acc11 += dot4(a1, b1); acc12 += dot4(a1, b2);
            acc20 += dot4(a2, b0); acc21 += dot4(a2, b1); acc22 += dot4(a2, b2);
        }
        float accs[3][3] = {{acc00, acc01, acc02}, {acc10, acc11, acc12}, {acc20, acc21, acc22}};
        #pragma unroll
        for (int a = 0; a < 3; ++a) {
            #pragma unroll
            for (int b = 0; b < 3; ++b) {
                int r = r0 + b;
                if (r < R_N) {
                    float v = accs[a][b];
                    sA[(w0 + a) * SA_STRIDE + r] = (v > 0.f) ? v : 0.1f * v;
                }
            }
        }
    }
    __syncthreads();

    // ---- Phase B2: per-column (r) norm over valid w, scale, softmax over w<L ----
    if (t < R_N) {
        const int r = t;
        float ssq = 0.f;
        for (int w = 0; w < L; ++w) { float a = sA[w * SA_STRIDE + r]; ssq += a * a; }
        float inv = LAM_SM / fmaxf(sqrtf(ssq), 1e-12f);
        float m = -1e30f;
        for (int w = 0; w < L; ++w) {
            float v = sA[w * SA_STRIDE + r] * inv;
            sA[w * SA_STRIDE + r] = v;
            m = fmaxf(m, v);
        }
        float s = 0.f;
        for (int w = 0; w < L; ++w) {
            float e = expf(sA[w * SA_STRIDE + r] - m);
            sA[w * SA_STRIDE + r] = e;
            s += e;
        }
        float is = 1.f / s;
        for (int w = 0; w < L; ++w) sA[w * SA_STRIDE + r] *= is;
    }
    __syncthreads();

    // ---- Phase C: wctx[r][:] = sum_w aw[w][r]*recipes[w][:]; reduce num/n1/n2 ----
    {
        const int wv = t >> 6;      // wave id 0..3
        const int lane = t & 63;    // d-chunk: d = 4*lane .. 4*lane+3
        const float* Rl = sR + 4 * lane;
        for (int r = wv; r < R_N; r += 4) {
            float4 wc = make_float4(0.f, 0.f, 0.f, 0.f);
            const float* Ap = sA + r;
            for (int w = 0; w < L; ++w) {
                float a = Ap[w * SA_STRIDE];            // wave-uniform broadcast
                float4 rv = *(const float4*)(Rl + w * SR_STRIDE);
                wc.x += a * rv.x; wc.y += a * rv.y; wc.z += a * rv.z; wc.w += a * rv.w;
            }
            float4 iv = *(const float4*)(sI + r * SR_STRIDE + 4 * lane);
            float np  = dot4(wc, iv);
            float n2p = dot4(wc, wc);
            float n1p = dot4(iv, iv);
            #pragma unroll
            for (int off = 32; off; off >>= 1) {
                np  += __shfl_xor(np,  off);
                n2p += __shfl_xor(n2p, off);
                n1p += __shfl_xor(n1p, off);
            }
            if (lane == 0) { numA[r] = np; n2A[r] = n2p; n1A[r] = n1p; }
        }
    }
    __syncthreads();

    // ---- Phase D: row_sim + logsumexp over r (first wave) ----
    if (t < 64) {
        float v = -1e30f;
        if (t < R_N) {
            float denom = fmaxf(sqrtf(n1A[t]) * sqrtf(n2A[t]), 1e-8f);
            v = LAM_LSE * (numA[t] / denom);
        }
        float m = v;
        #pragma unroll
        for (int off = 32; off; off >>= 1) m = fmaxf(m, __shfl_xor(m, off));
        float e = (t < R_N) ? expf(v - m) : 0.f;
        #pragma unroll
        for (int off = 32; off; off >>= 1) e += __shfl_xor(e, off);
        if (t == 0) scores[(size_t)i * C_N + c] = (m + logf(e)) / LAM_LSE;
    }
}

__global__ __launch_bounds__(256) void hinge_loss_kernel(
    const float* __restrict__ S, float* __restrict__ out)
{
    __shared__ float diag[96];
    __shared__ float wsum[4];
    const int t = threadIdx.x;
    if (t < 96) diag[t] = S[t * 97];
    __syncthreads();
    float acc = 0.f;
    for (int k = t; k < 96 * 96; k += 256) {
        int ii = k / 96;
        int cc = k - ii * 96;
        if (ii != cc) {
            float s = S[k];
            acc += fmaxf(MARGIN_F + s - diag[cc], 0.f)
                 + fmaxf(MARGIN_F + s - diag[ii], 0.f);
        }
    }
    #pragma unroll
    for (int off = 32; off; off >>= 1) acc += __shfl_xor(acc, off);
    if ((t & 63) == 0) wsum[t >> 6] = acc;
    __syncthreads();
    if (t == 0) out[0] = wsum[0] + wsum[1] + wsum[2] + wsum[3];
}

extern "C" void kernel_launch(void* const* d_in, const int* in_sizes, int n_in,
                              void* d_out, int out_size, void* d_ws, size_t ws_size,
                              hipStream_t stream) {
    const float* images  = (const float*)d_in[0];
    const float* recipes = (const float*)d_in[1];
    const int*   caps    = (const int*)d_in[2];
    float* out = (float*)d_out;
    float* scores = (float*)d_ws;   // 96*96 floats

    hipLaunchKernelGGL(xattn_pair_kernel, dim3(I_N * C_N), dim3(256), 0, stream,
                       images, recipes, caps, scores);
    hipLaunchKernelGGL(hinge_loss_kernel, dim3(1), dim3(256), 0, stream, scores, out);
}

// Round 2
// 293.330 us; speedup vs baseline: 3.2789x; 3.2789x over previous
//
#include <hip/hip_runtime.h>
#include <math.h>

#define I_N 96
#define C_N 96
#define R_N 36
#define W_N 48
#define D_N 256
#define NIMG 8
#define NCOL (NIMG * R_N)      // 288
#define NTILE (I_N / NIMG)     // 12
#define LAM_SM 9.0f
#define LAM_LSE 6.0f
#define MARGIN_F 0.2f

// workspace layout (float offsets)
#define WS_N1 0                    // 3456 floats
#define WS_G 4096                  // 96*48*48 = 221184 floats
#define WS_SC 225280               // 96*96 = 9216 floats

#define SI_STRIDE 36               // floats per staged row (32 data + 4 pad)
#define SG_STRIDE 52               // padded G row
#define LDSF 12160                 // 48,640 B -> 3 blocks/CU

__device__ __forceinline__ float dot4(float4 a, float4 b) {
    return a.x * b.x + a.y * b.y + a.z * b.z + a.w * b.w;
}
__device__ __forceinline__ float grp16_sum(float v) {
    v += __shfl_xor(v, 1); v += __shfl_xor(v, 2);
    v += __shfl_xor(v, 4); v += __shfl_xor(v, 8);
    return v;
}
__device__ __forceinline__ float grp16_max(float v) {
    v = fmaxf(v, __shfl_xor(v, 1)); v = fmaxf(v, __shfl_xor(v, 2));
    v = fmaxf(v, __shfl_xor(v, 4)); v = fmaxf(v, __shfl_xor(v, 8));
    return v;
}
__device__ __forceinline__ unsigned short f32_to_bf16(float f) {
    unsigned int u = __float_as_uint(f);
    return (unsigned short)((u + 0x7fffu + ((u >> 16) & 1u)) >> 16);
}
__device__ __forceinline__ float bf16_to_f32(unsigned short h) {
    return __uint_as_float((unsigned int)h << 16);
}

// ---- prep: n1sq[i*36+r] = ||images[i,r]||^2 ----
__global__ __launch_bounds__(256) void prep_n1(const float* __restrict__ images,
                                               float* __restrict__ n1sq) {
    int row = blockIdx.x * 256 + threadIdx.x;
    if (row >= I_N * R_N) return;
    const float4* p = (const float4*)(images + (size_t)row * D_N);
    float s = 0.f;
    #pragma unroll 8
    for (int k = 0; k < D_N / 4; ++k) { float4 v = p[k]; s += dot4(v, v); }
    n1sq[row] = s;
}

// ---- prep: G[c][w][w'] = recipes[c,w] . recipes[c,w'] ----
#define GR_STRIDE 260
__global__ __launch_bounds__(256) void prep_G(const float* __restrict__ recipes,
                                              float* __restrict__ G) {
    __shared__ float sR[W_N * GR_STRIDE];
    const int c = blockIdx.x, t = threadIdx.x;
    const float4* src = (const float4*)(recipes + (size_t)c * W_N * D_N);
    for (int k = t; k < W_N * D_N / 4; k += 256) {
        int w = k >> 6, d4 = k & 63;
        *(float4*)(sR + w * GR_STRIDE + 4 * d4) = src[k];
    }
    __syncthreads();
    const int tw = t & 15, tv = t >> 4;
    float acc[3][3];
    #pragma unroll
    for (int a = 0; a < 3; ++a)
        #pragma unroll
        for (int b = 0; b < 3; ++b) acc[a][b] = 0.f;
    const float* A = sR + 3 * tw * GR_STRIDE;
    const float* B = sR + 3 * tv * GR_STRIDE;
    for (int d4 = 0; d4 < 64; ++d4) {
        float4 a0 = *(const float4*)(A + 4 * d4);
        float4 a1 = *(const float4*)(A + GR_STRIDE + 4 * d4);
        float4 a2 = *(const float4*)(A + 2 * GR_STRIDE + 4 * d4);
        float4 b0 = *(const float4*)(B + 4 * d4);
        float4 b1 = *(const float4*)(B + GR_STRIDE + 4 * d4);
        float4 b2 = *(const float4*)(B + 2 * GR_STRIDE + 4 * d4);
        acc[0][0] += dot4(a0, b0); acc[0][1] += dot4(a0, b1); acc[0][2] += dot4(a0, b2);
        acc[1][0] += dot4(a1, b0); acc[1][1] += dot4(a1, b1); acc[1][2] += dot4(a1, b2);
        acc[2][0] += dot4(a2, b0); acc[2][1] += dot4(a2, b1); acc[2][2] += dot4(a2, b2);
    }
    float* Gc = G + (size_t)c * W_N * W_N;
    #pragma unroll
    for (int a = 0; a < 3; ++a)
        #pragma unroll
        for (int b = 0; b < 3; ++b)
            Gc[(3 * tw + a) * W_N + (3 * tv + b)] = acc[a][b];
}

// ---- main: per (caption, 8-image tile) ----
__global__ __launch_bounds__(256) void xattn_main(
    const float* __restrict__ images, const float* __restrict__ recipes,
    const int* __restrict__ cap_lens, const float* __restrict__ n1sq,
    const float* __restrict__ G, float* __restrict__ scores)
{
    __shared__ float lds[LDSF];
    float* sI = lds;                              // [288][36] (GEMM phase)
    float* sR = lds + NCOL * SI_STRIDE;           // 10368: [48][36]
    unsigned short* sAW = (unsigned short*)lds;   // [288][48] bf16 (post phase)
    float* sG = lds + 6912;                       // [48][52]
    float* sRS = lds + 6912 + W_N * SG_STRIDE;    // 9408: [288]

    const int t = threadIdx.x;
    const int tw = t & 15;        // w = 3*tw + a
    const int tn = t >> 4;        // n = tn + 16*j
    const int bid = blockIdx.x;
    const int c = bid % C_N;
    const int i0 = (bid / C_N) * NIMG;
    const int L = cap_lens[c];

    const float* imgB = images + (size_t)i0 * R_N * D_N;
    const float* recB = recipes + (size_t)c * W_N * D_N;

    float acc[3][18];
    #pragma unroll
    for (int a = 0; a < 3; ++a)
        #pragma unroll
        for (int j = 0; j < 18; ++j) acc[a][j] = 0.f;

    // ---- GEMM1: raw[w][n] = recipes . images, K streamed in chunks of 32 ----
    for (int ch = 0; ch < 8; ++ch) {
        const int d0 = ch * 32;
        #pragma unroll
        for (int m = 0; m < 9; ++m) {           // 288 rows * 8 f4
            int k = t + 256 * m;
            int row = k >> 3, c4 = k & 7;
            *(float4*)(sI + row * SI_STRIDE + 4 * c4) =
                *(const float4*)(imgB + row * D_N + d0 + 4 * c4);
        }
        {
            int row = t >> 3, c4 = t & 7;       // 48 rows * 8 f4 = 384
            *(float4*)(sR + row * SI_STRIDE + 4 * c4) =
                *(const float4*)(recB + row * D_N + d0 + 4 * c4);
            if (t < 128) {
                int k = t + 256; row = k >> 3; c4 = k & 7;
                *(float4*)(sR + row * SI_STRIDE + 4 * c4) =
                    *(const float4*)(recB + row * D_N + d0 + 4 * c4);
            }
        }
        __syncthreads();
        #pragma unroll 2
        for (int d4 = 0; d4 < 8; ++d4) {
            float4 a0 = *(const float4*)(sR + (3 * tw + 0) * SI_STRIDE + 4 * d4);
            float4 a1 = *(const float4*)(sR + (3 * tw + 1) * SI_STRIDE + 4 * d4);
            float4 a2 = *(const float4*)(sR + (3 * tw + 2) * SI_STRIDE + 4 * d4);
            #pragma unroll
            for (int j = 0; j < 18; ++j) {
                float4 b = *(const float4*)(sI + (tn + 16 * j) * SI_STRIDE + 4 * d4);
                acc[0][j] += dot4(a0, b);
                acc[1][j] += dot4(a1, b);
                acc[2][j] += dot4(a2, b);
            }
        }
        __syncthreads();
    }

    // ---- per-column leaky/norm/softmax; num = sum aw*raw; write awT (bf16) ----
    float num_col[18];
    #pragma unroll
    for (int j = 0; j < 18; ++j) {
        const int n = tn + 16 * j;
        float lk[3], v[3], e[3];
        #pragma unroll
        for (int a = 0; a < 3; ++a) {
            float r = acc[a][j];
            float l = (r > 0.f) ? r : 0.1f * r;
            lk[a] = (3 * tw + a < L) ? l : 0.f;
        }
        float ssq = lk[0] * lk[0] + lk[1] * lk[1] + lk[2] * lk[2];
        ssq = grp16_sum(ssq);
        float inv = LAM_SM / fmaxf(sqrtf(ssq), 1e-12f);
        #pragma unroll
        for (int a = 0; a < 3; ++a)
            v[a] = (3 * tw + a < L) ? lk[a] * inv : -1e30f;
        float m = fmaxf(v[0], fmaxf(v[1], v[2]));
        m = grp16_max(m);
        #pragma unroll
        for (int a = 0; a < 3; ++a)
            e[a] = (3 * tw + a < L) ? __expf(v[a] - m) : 0.f;
        float s = e[0] + e[1] + e[2];
        s = grp16_sum(s);
        float is = 1.f / s;
        float np = 0.f;
        #pragma unroll
        for (int a = 0; a < 3; ++a) {
            float aw = e[a] * is;
            np += aw * acc[a][j];
            sAW[n * W_N + 3 * tw + a] = f32_to_bf16(aw);
        }
        num_col[j] = grp16_sum(np);
    }
    // stage G[c] into padded LDS
    {
        const float* Gc = G + (size_t)c * W_N * W_N;
        for (int k = t; k < 576; k += 256) {
            int w = k / 12;
            int w4 = (k % 12) * 4;
            *(float4*)(sG + w * SG_STRIDE + w4) = *(const float4*)(Gc + w * W_N + w4);
        }
    }
    __syncthreads();

    // ---- H-GEMM: H[w][n] = sum_w' G[w][w'] aw[w'][n]  (K=48) ----
    float acc2[3][18];
    #pragma unroll
    for (int a = 0; a < 3; ++a)
        #pragma unroll
        for (int j = 0; j < 18; ++j) acc2[a][j] = 0.f;
    for (int k4 = 0; k4 < 12; ++k4) {
        float4 g0 = *(const float4*)(sG + (3 * tw + 0) * SG_STRIDE + 4 * k4);
        float4 g1 = *(const float4*)(sG + (3 * tw + 1) * SG_STRIDE + 4 * k4);
        float4 g2 = *(const float4*)(sG + (3 * tw + 2) * SG_STRIDE + 4 * k4);
        #pragma unroll
        for (int j = 0; j < 18; ++j) {
            const int n = tn + 16 * j;
            uint2 u = *(const uint2*)(sAW + n * W_N + 4 * k4);
            float b0 = __uint_as_float(u.x << 16);
            float b1 = __uint_as_float(u.x & 0xffff0000u);
            float b2 = __uint_as_float(u.y << 16);
            float b3 = __uint_as_float(u.y & 0xffff0000u);
            acc2[0][j] += g0.x * b0 + g0.y * b1 + g0.z * b2 + g0.w * b3;
            acc2[1][j] += g1.x * b0 + g1.y * b1 + g1.z * b2 + g1.w * b3;
            acc2[2][j] += g2.x * b0 + g2.y * b1 + g2.z * b2 + g2.w * b3;
        }
    }

    // ---- n2 = aw . H per column; row_sim ----
    #pragma unroll
    for (int j = 0; j < 18; ++j) {
        const int n = tn + 16 * j;
        float n2p = 0.f;
        #pragma unroll
        for (int a = 0; a < 3; ++a) {
            float aw = bf16_to_f32(sAW[n * W_N + 3 * tw + a]);
            n2p += aw * acc2[a][j];
        }
        n2p = grp16_sum(n2p);
        if (tw == 0) {
            float n1 = n1sq[i0 * R_N + n];
            float denom = fmaxf(sqrtf(n1) * sqrtf(n2p), 1e-8f);
            sRS[n] = num_col[j] / denom;
        }
    }
    __syncthreads();

    // ---- LSE over r per image; write scores[i][c] ----
    if (t < 64) {
        const int ii = t >> 3, k = t & 7;
        float mx = -1e30f;
        #pragma unroll
        for (int q = 0; q < 5; ++q) {
            int r = k + 8 * q;
            if (r < R_N) mx = fmaxf(mx, sRS[ii * R_N + r]);
        }
        mx = fmaxf(mx, __shfl_xor(mx, 1));
        mx = fmaxf(mx, __shfl_xor(mx, 2));
        mx = fmaxf(mx, __shfl_xor(mx, 4));
        float s = 0.f;
        #pragma unroll
        for (int q = 0; q < 5; ++q) {
            int r = k + 8 * q;
            if (r < R_N) s += __expf(LAM_LSE * sRS[ii * R_N + r] - LAM_LSE * mx);
        }
        s += __shfl_xor(s, 1);
        s += __shfl_xor(s, 2);
        s += __shfl_xor(s, 4);
        if (k == 0)
            scores[(size_t)(i0 + ii) * C_N + c] = (LAM_LSE * mx + __logf(s)) / LAM_LSE;
    }
}

__global__ __launch_bounds__(256) void hinge_loss_kernel(
    const float* __restrict__ S, float* __restrict__ out)
{
    __shared__ float diag[96];
    __shared__ float wsum[4];
    const int t = threadIdx.x;
    if (t < 96) diag[t] = S[t * 97];
    __syncthreads();
    float acc = 0.f;
    for (int k = t; k < 96 * 96; k += 256) {
        int ii = k / 96;
        int cc = k - ii * 96;
        if (ii != cc) {
            float s = S[k];
            acc += fmaxf(MARGIN_F + s - diag[cc], 0.f)
                 + fmaxf(MARGIN_F + s - diag[ii], 0.f);
        }
    }
    #pragma unroll
    for (int off = 32; off; off >>= 1) acc += __shfl_xor(acc, off);
    if ((t & 63) == 0) wsum[t >> 6] = acc;
    __syncthreads();
    if (t == 0) out[0] = wsum[0] + wsum[1] + wsum[2] + wsum[3];
}

extern "C" void kernel_launch(void* const* d_in, const int* in_sizes, int n_in,
                              void* d_out, int out_size, void* d_ws, size_t ws_size,
                              hipStream_t stream) {
    const float* images  = (const float*)d_in[0];
    const float* recipes = (const float*)d_in[1];
    const int*   caps    = (const int*)d_in[2];
    float* out = (float*)d_out;
    float* wsf = (float*)d_ws;

    hipLaunchKernelGGL(prep_n1, dim3((I_N * R_N + 255) / 256), dim3(256), 0, stream,
                       images, wsf + WS_N1);
    hipLaunchKernelGGL(prep_G, dim3(C_N), dim3(256), 0, stream,
                       recipes, wsf + WS_G);
    hipLaunchKernelGGL(xattn_main, dim3(C_N * NTILE), dim3(256), 0, stream,
                       images, recipes, caps, wsf + WS_N1, wsf + WS_G, wsf + WS_SC);
    hipLaunchKernelGGL(hinge_loss_kernel, dim3(1), dim3(256), 0, stream,
                       wsf + WS_SC, out);
}

// Round 3
// 83.875 us; speedup vs baseline: 11.4670x; 3.4972x over previous
//
#include <hip/hip_runtime.h>
#include <math.h>

#define I_N 96
#define C_N 96
#define R_N 36
#define W_N 48
#define D_N 256
#define NIMG 4
#define NCOL (NIMG * R_N)   // 144
#define NTILE (I_N / NIMG)  // 24
#define LAM_SM 9.0f
#define LAM_LSE 6.0f
#define MARGIN_F 0.2f
#define AWS 72              // aw LDS row stride (shorts): 144B -> 2-way conflict only
#define GS 64               // G row stride (shorts), K padded 48->64 with zeros

#define IMG_ELEMS (I_N * R_N * D_N)   // 884736
#define REC_ELEMS (C_N * W_N * D_N)   // 1179648
#define NT4 ((IMG_ELEMS + REC_ELEMS) / 4)  // 516096

// workspace layout
#define WSF_SCORES 0          // 9216 floats
#define WSF_N1     9216       // 3456 floats
#define WSF_SHBASE 12800      // shorts begin here (51200 B, 256-aligned)
#define SH_IMG 0
#define SH_REC IMG_ELEMS
#define SH_G   (IMG_ELEMS + REC_ELEMS)

typedef __attribute__((ext_vector_type(8))) short short8;
typedef __attribute__((ext_vector_type(4))) float f32x4;

#define MFMA16(a, b, c) __builtin_amdgcn_mfma_f32_16x16x32_bf16(a, b, c, 0, 0, 0)

__device__ __forceinline__ unsigned short f32_to_bf16(float f) {
    unsigned int u = __float_as_uint(f);
    return (unsigned short)((u + 0x7fffu + ((u >> 16) & 1u)) >> 16);
}
__device__ __forceinline__ float dot4f(float4 a, float4 b) {
    return a.x * b.x + a.y * b.y + a.z * b.z + a.w * b.w;
}

// ---- convert images+recipes fp32 -> bf16 ----
__global__ __launch_bounds__(256) void prep_cvt(const float* __restrict__ imgs,
        const float* __restrict__ recs, unsigned short* __restrict__ img_b,
        unsigned short* __restrict__ rec_b) {
    int k = blockIdx.x * 256 + threadIdx.x;
    const int NI4 = IMG_ELEMS / 4;
    if (k >= NT4) return;
    float4 v = (k < NI4) ? ((const float4*)imgs)[k] : ((const float4*)recs)[k - NI4];
    ushort4 o;
    o.x = f32_to_bf16(v.x); o.y = f32_to_bf16(v.y);
    o.z = f32_to_bf16(v.z); o.w = f32_to_bf16(v.w);
    if (k < NI4) ((ushort4*)img_b)[k] = o;
    else ((ushort4*)rec_b)[k - NI4] = o;
}

// ---- n1sq[i*36+r] = ||images[i,r]||^2 (fp32 exact) ----
__global__ __launch_bounds__(256) void prep_n1(const float* __restrict__ images,
                                               float* __restrict__ n1sq) {
    int row = blockIdx.x * 256 + threadIdx.x;
    if (row >= I_N * R_N) return;
    const float4* p = (const float4*)(images + (size_t)row * D_N);
    float s = 0.f;
    #pragma unroll 8
    for (int k = 0; k < D_N / 4; ++k) { float4 v = p[k]; s += dot4f(v, v); }
    n1sq[row] = s;
}

// ---- G[c] = R.R^T in bf16, [48][64] K-padded with zeros, via MFMA ----
__global__ __launch_bounds__(64) void prep_G(const unsigned short* __restrict__ rec_b,
                                             unsigned short* __restrict__ G) {
    const int c = blockIdx.x, l = threadIdx.x;
    const int li = l & 15, q = l >> 4;
    const unsigned short* base = rec_b + (size_t)c * W_N * D_N + li * D_N + 8 * q;
    f32x4 acc[3][3];
    #pragma unroll
    for (int m = 0; m < 3; ++m)
        #pragma unroll
        for (int j = 0; j < 3; ++j) acc[m][j] = (f32x4){0.f, 0.f, 0.f, 0.f};
    #pragma unroll
    for (int ks = 0; ks < 8; ++ks) {
        short8 a[3];
        #pragma unroll
        for (int m = 0; m < 3; ++m)
            a[m] = *(const short8*)(base + m * 16 * D_N + 32 * ks);
        #pragma unroll
        for (int m = 0; m < 3; ++m)
            #pragma unroll
            for (int j = 0; j < 3; ++j)
                acc[m][j] = MFMA16(a[m], a[j], acc[m][j]);
    }
    unsigned short* Gc = G + (size_t)c * W_N * GS;
    #pragma unroll
    for (int m = 0; m < 3; ++m)
        #pragma unroll
        for (int j = 0; j < 3; ++j)
            #pragma unroll
            for (int r = 0; r < 4; ++r)
                Gc[(16 * m + 4 * q + r) * GS + 16 * j + li] = f32_to_bf16(acc[m][j][r]);
    if (l < 48) {
        uint4 z = make_uint4(0u, 0u, 0u, 0u);
        *(uint4*)(Gc + l * GS + 48) = z;
        *(uint4*)(Gc + l * GS + 56) = z;
    }
}

// ---- main: (caption, 4-image tile), 3 waves, MFMA GEMM1 + softmax + MFMA H-GEMM ----
__global__ __launch_bounds__(192) void xattn_main(
    const unsigned short* __restrict__ img_b, const unsigned short* __restrict__ rec_b,
    const unsigned short* __restrict__ G, const int* __restrict__ cap_lens,
    const float* __restrict__ n1sq, float* __restrict__ scores)
{
    __shared__ __align__(16) unsigned short awL[NCOL * AWS];  // 20736 B
    __shared__ float rs[NCOL];

    const int t = threadIdx.x;
    const int wv = t >> 6;
    const int l = t & 63;
    const int li = l & 15, q = l >> 4;
    const int c = blockIdx.x % C_N;
    const int i0 = (blockIdx.x / C_N) * NIMG;
    const int L = cap_lens[c];
    const int n0 = wv * 48;

    // zero the K-pad region awL[:, 48:64)
    for (int k = t; k < NCOL * 4; k += 192) {
        int row = k >> 2, s = k & 3;
        *(uint2*)(awL + row * AWS + 48 + s * 4) = make_uint2(0u, 0u);
    }

    // ---- Phase 1: raw[w][n] = recipes . images^T  (M=48, N=48/wave, K=256) ----
    f32x4 acc[3][3];
    #pragma unroll
    for (int m = 0; m < 3; ++m)
        #pragma unroll
        for (int j = 0; j < 3; ++j) acc[m][j] = (f32x4){0.f, 0.f, 0.f, 0.f};
    const unsigned short* pa = rec_b + (size_t)c * W_N * D_N + li * D_N + 8 * q;
    const unsigned short* pb = img_b + (size_t)(i0 * R_N + n0 + li) * D_N + 8 * q;
    #pragma unroll
    for (int ks = 0; ks < 8; ++ks) {
        short8 a[3], b[3];
        #pragma unroll
        for (int m = 0; m < 3; ++m) a[m] = *(const short8*)(pa + m * 16 * D_N + 32 * ks);
        #pragma unroll
        for (int j = 0; j < 3; ++j) b[j] = *(const short8*)(pb + j * 16 * D_N + 32 * ks);
        #pragma unroll
        for (int m = 0; m < 3; ++m)
            #pragma unroll
            for (int j = 0; j < 3; ++j)
                acc[m][j] = MFMA16(a[m], b[j], acc[m][j]);
    }

    // ---- Phase 2: per-column leaky/norm/softmax in C-frag layout ----
    // lane holds raw[w = 16m + 4q + r][n = n0 + 16j + li]
    f32x4 aw[3][3];
    float numc[3];
    #pragma unroll
    for (int j = 0; j < 3; ++j) {
        float tmp[3][4];
        float ssq = 0.f;
        #pragma unroll
        for (int m = 0; m < 3; ++m)
            #pragma unroll
            for (int r = 0; r < 4; ++r) {
                int w = 16 * m + 4 * q + r;
                float x = acc[m][j][r];
                float lv = (x > 0.f) ? x : 0.1f * x;
                lv = (w < L) ? lv : 0.f;
                tmp[m][r] = lv;
                ssq += lv * lv;
            }
        ssq += __shfl_xor(ssq, 16); ssq += __shfl_xor(ssq, 32);
        float inv = LAM_SM / fmaxf(sqrtf(ssq), 1e-12f);
        float mx = -1e30f;
        #pragma unroll
        for (int m = 0; m < 3; ++m)
            #pragma unroll
            for (int r = 0; r < 4; ++r) {
                int w = 16 * m + 4 * q + r;
                float vv = (w < L) ? tmp[m][r] * inv : -1e30f;
                tmp[m][r] = vv;
                mx = fmaxf(mx, vv);
            }
        mx = fmaxf(mx, __shfl_xor(mx, 16)); mx = fmaxf(mx, __shfl_xor(mx, 32));
        float s = 0.f;
        #pragma unroll
        for (int m = 0; m < 3; ++m)
            #pragma unroll
            for (int r = 0; r < 4; ++r) {
                int w = 16 * m + 4 * q + r;
                float e = (w < L) ? __expf(tmp[m][r] - mx) : 0.f;
                tmp[m][r] = e;
                s += e;
            }
        s += __shfl_xor(s, 16); s += __shfl_xor(s, 32);
        float is = 1.f / s;
        float np = 0.f;
        #pragma unroll
        for (int m = 0; m < 3; ++m)
            #pragma unroll
            for (int r = 0; r < 4; ++r) {
                float a = tmp[m][r] * is;
                aw[m][j][r] = a;
                np += a * acc[m][j][r];   // raw pre-activation dot -> num
            }
        np += __shfl_xor(np, 16); np += __shfl_xor(np, 32);
        numc[j] = np;
        // write aw transposed [n][w] bf16 (B-operand of H-GEMM)
        int n = n0 + 16 * j + li;
        #pragma unroll
        for (int m = 0; m < 3; ++m) {
            unsigned int lo = (unsigned)f32_to_bf16(aw[m][j][0]) |
                              ((unsigned)f32_to_bf16(aw[m][j][1]) << 16);
            unsigned int hi = (unsigned)f32_to_bf16(aw[m][j][2]) |
                              ((unsigned)f32_to_bf16(aw[m][j][3]) << 16);
            *(uint2*)(awL + n * AWS + 16 * m + 4 * q) = make_uint2(lo, hi);
        }
    }
    __syncthreads();

    // ---- Phase 3: H[w][n] = G . aw  (K=64 padded), reuse acc ----
    #pragma unroll
    for (int m = 0; m < 3; ++m)
        #pragma unroll
        for (int j = 0; j < 3; ++j) acc[m][j] = (f32x4){0.f, 0.f, 0.f, 0.f};
    const unsigned short* pg = G + (size_t)c * W_N * GS + li * GS + 8 * q;
    #pragma unroll
    for (int ks = 0; ks < 2; ++ks) {
        short8 a[3], b[3];
        #pragma unroll
        for (int m = 0; m < 3; ++m) a[m] = *(const short8*)(pg + m * 16 * GS + 32 * ks);
        #pragma unroll
        for (int j = 0; j < 3; ++j)
            b[j] = *(const short8*)(awL + (n0 + 16 * j + li) * AWS + 32 * ks + 8 * q);
        #pragma unroll
        for (int m = 0; m < 3; ++m)
            #pragma unroll
            for (int j = 0; j < 3; ++j)
                acc[m][j] = MFMA16(a[m], b[j], acc[m][j]);
    }

    // ---- Phase 4: n2 = aw.H per column; row_sim ----
    #pragma unroll
    for (int j = 0; j < 3; ++j) {
        float n2p = 0.f;
        #pragma unroll
        for (int m = 0; m < 3; ++m)
            #pragma unroll
            for (int r = 0; r < 4; ++r)
                n2p += aw[m][j][r] * acc[m][j][r];
        n2p += __shfl_xor(n2p, 16); n2p += __shfl_xor(n2p, 32);
        if (q == 0) {
            int n = n0 + 16 * j + li;
            float n1 = n1sq[i0 * R_N + n];
            float denom = fmaxf(sqrtf(n1) * sqrtf(n2p), 1e-8f);
            rs[n] = numc[j] / denom;
        }
    }
    __syncthreads();

    // ---- Phase 5: LSE over r per image ----
    if (t < 32) {
        int ii = t >> 3, k = t & 7;
        float mx = -1e30f;
        #pragma unroll
        for (int p = 0; p < 5; ++p) {
            int r = k + 8 * p;
            if (r < R_N) mx = fmaxf(mx, rs[ii * R_N + r]);
        }
        mx = fmaxf(mx, __shfl_xor(mx, 1));
        mx = fmaxf(mx, __shfl_xor(mx, 2));
        mx = fmaxf(mx, __shfl_xor(mx, 4));
        float s = 0.f;
        #pragma unroll
        for (int p = 0; p < 5; ++p) {
            int r = k + 8 * p;
            if (r < R_N) s += __expf(LAM_LSE * (rs[ii * R_N + r] - mx));
        }
        s += __shfl_xor(s, 1); s += __shfl_xor(s, 2); s += __shfl_xor(s, 4);
        if (k == 0)
            scores[(size_t)(i0 + ii) * C_N + c] = (LAM_LSE * mx + __logf(s)) / LAM_LSE;
    }
}

__global__ __launch_bounds__(256) void hinge_loss_kernel(
    const float* __restrict__ S, float* __restrict__ out)
{
    __shared__ float diag[96];
    __shared__ float wsum[4];
    const int t = threadIdx.x;
    if (t < 96) diag[t] = S[t * 97];
    __syncthreads();
    float acc = 0.f;
    for (int k = t; k < 96 * 96; k += 256) {
        int ii = k / 96;
        int cc = k - ii * 96;
        if (ii != cc) {
            float s = S[k];
            acc += fmaxf(MARGIN_F + s - diag[cc], 0.f)
                 + fmaxf(MARGIN_F + s - diag[ii], 0.f);
        }
    }
    #pragma unroll
    for (int off = 32; off; off >>= 1) acc += __shfl_xor(acc, off);
    if ((t & 63) == 0) wsum[t >> 6] = acc;
    __syncthreads();
    if (t == 0) out[0] = wsum[0] + wsum[1] + wsum[2] + wsum[3];
}

extern "C" void kernel_launch(void* const* d_in, const int* in_sizes, int n_in,
                              void* d_out, int out_size, void* d_ws, size_t ws_size,
                              hipStream_t stream) {
    const float* images  = (const float*)d_in[0];
    const float* recipes = (const float*)d_in[1];
    const int*   caps    = (const int*)d_in[2];
    float* out = (float*)d_out;
    float* wsf = (float*)d_ws;
    float* scores = wsf + WSF_SCORES;
    float* n1 = wsf + WSF_N1;
    unsigned short* shb = (unsigned short*)(wsf + WSF_SHBASE);
    unsigned short* img_b = shb + SH_IMG;
    unsigned short* rec_b = shb + SH_REC;
    unsigned short* Gb    = shb + SH_G;

    hipLaunchKernelGGL(prep_cvt, dim3((NT4 + 255) / 256), dim3(256), 0, stream,
                       images, recipes, img_b, rec_b);
    hipLaunchKernelGGL(prep_n1, dim3((I_N * R_N + 255) / 256), dim3(256), 0, stream,
                       images, n1);
    hipLaunchKernelGGL(prep_G, dim3(C_N), dim3(64), 0, stream, rec_b, Gb);
    hipLaunchKernelGGL(xattn_main, dim3(C_N * NTILE), dim3(192), 0, stream,
                       img_b, rec_b, Gb, caps, n1, scores);
    hipLaunchKernelGGL(hinge_loss_kernel, dim3(1), dim3(256), 0, stream, scores, out);
}

// Round 4
// 56.017 us; speedup vs baseline: 17.1697x; 1.4973x over previous
//
#include <hip/hip_runtime.h>
#include <math.h>

#define I_N 96
#define C_N 96
#define R_N 36
#define W_N 48
#define D_N 256
#define NIMG 4
#define NCOL (NIMG * R_N)   // 144
#define NTILE (I_N / NIMG)  // 24
#define LAM_SM 9.0f
#define LAM_LSE 6.0f
#define MARGIN_F 0.2f
#define AWS 72              // aw LDS row stride (shorts)
#define GS 64               // G row stride (shorts), K padded 48->64 with zeros

#define IMG_ELEMS (I_N * R_N * D_N)   // 884736
#define REC_ELEMS (C_N * W_N * D_N)   // 1179648

// workspace layout
#define WSF_SCORES 0          // 9216 floats
#define WSF_N1     9216       // 3456 floats
#define WSF_SHBASE 12800      // shorts begin here
#define SH_IMG 0
#define SH_REC IMG_ELEMS
#define SH_G   (IMG_ELEMS + REC_ELEMS)

typedef __attribute__((ext_vector_type(8))) short short8;
typedef __attribute__((ext_vector_type(4))) float f32x4;

#define MFMA16(a, b, c) __builtin_amdgcn_mfma_f32_16x16x32_bf16(a, b, c, 0, 0, 0)

__device__ __forceinline__ unsigned short f32_to_bf16(float f) {
    unsigned int u = __float_as_uint(f);
    return (unsigned short)((u + 0x7fffu + ((u >> 16) & 1u)) >> 16);
}
__device__ __forceinline__ float dot4f(float4 a, float4 b) {
    return a.x * b.x + a.y * b.y + a.z * b.z + a.w * b.w;
}
__device__ __forceinline__ uint4 cvt8u(float4 v0, float4 v1) {
    uint4 o;
    o.x = (unsigned)f32_to_bf16(v0.x) | ((unsigned)f32_to_bf16(v0.y) << 16);
    o.y = (unsigned)f32_to_bf16(v0.z) | ((unsigned)f32_to_bf16(v0.w) << 16);
    o.z = (unsigned)f32_to_bf16(v1.x) | ((unsigned)f32_to_bf16(v1.y) << 16);
    o.w = (unsigned)f32_to_bf16(v1.z) | ((unsigned)f32_to_bf16(v1.w) << 16);
    return o;
}
__device__ __forceinline__ short8 cvt8s(float4 v0, float4 v1) {
    short8 s;
    s[0] = (short)f32_to_bf16(v0.x); s[1] = (short)f32_to_bf16(v0.y);
    s[2] = (short)f32_to_bf16(v0.z); s[3] = (short)f32_to_bf16(v0.w);
    s[4] = (short)f32_to_bf16(v1.x); s[5] = (short)f32_to_bf16(v1.y);
    s[6] = (short)f32_to_bf16(v1.z); s[7] = (short)f32_to_bf16(v1.w);
    return s;
}

// ---- one fused prep dispatch ----
// blocks [0,24): img cvt->packed frags   [24,120): rec cvt->packed frags
// blocks [120,216): Gram via MFMA (fp32 src, inline cvt)   [216,230): n1sq
__global__ __launch_bounds__(256) void prep_all(
    const float* __restrict__ images, const float* __restrict__ recipes,
    unsigned short* __restrict__ img_p, unsigned short* __restrict__ rec_p,
    unsigned short* __restrict__ G, float* __restrict__ n1sq)
{
    const int bid = blockIdx.x;
    const int t = threadIdx.x;
    const int wv = t >> 6, l = t & 63;
    const int li = l & 15, q = l >> 4;

    if (bid < 24) {
        // packed img: frag f = rg*8+ks (rg in [0,9)); value[l][e] =
        //   img[row = bid*144 + rg*16 + li][col = ks*32 + q*8 + e]
        const float* src = images + (size_t)bid * NCOL * D_N;
        unsigned short* dst = img_p + (size_t)bid * 72 * 512;
        #pragma unroll
        for (int ff = 0; ff < 18; ++ff) {
            int f = wv * 18 + ff;
            int rg = f >> 3, ks = f & 7;
            const float* p = src + (rg * 16 + li) * D_N + ks * 32 + q * 8;
            float4 v0 = *(const float4*)p;
            float4 v1 = *(const float4*)(p + 4);
            *(uint4*)(dst + (size_t)f * 512 + l * 8) = cvt8u(v0, v1);
        }
    } else if (bid < 120) {
        const int c = bid - 24;
        const float* src = recipes + (size_t)c * W_N * D_N;
        unsigned short* dst = rec_p + (size_t)c * 24 * 512;
        #pragma unroll
        for (int ff = 0; ff < 6; ++ff) {
            int f = wv * 6 + ff;
            int m = f >> 3, ks = f & 7;
            const float* p = src + (m * 16 + li) * D_N + ks * 32 + q * 8;
            float4 v0 = *(const float4*)p;
            float4 v1 = *(const float4*)(p + 4);
            *(uint4*)(dst + (size_t)f * 512 + l * 8) = cvt8u(v0, v1);
        }
    } else if (bid < 216) {
        const int c = bid - 120;
        if (wv == 0) {
            const float* src = recipes + (size_t)c * W_N * D_N;
            f32x4 acc[3][3];
            #pragma unroll
            for (int m = 0; m < 3; ++m)
                #pragma unroll
                for (int j = 0; j < 3; ++j) acc[m][j] = (f32x4){0.f, 0.f, 0.f, 0.f};
            #pragma unroll
            for (int ks = 0; ks < 8; ++ks) {
                short8 a[3];
                #pragma unroll
                for (int m = 0; m < 3; ++m) {
                    const float* p = src + (m * 16 + li) * D_N + ks * 32 + q * 8;
                    a[m] = cvt8s(*(const float4*)p, *(const float4*)(p + 4));
                }
                #pragma unroll
                for (int m = 0; m < 3; ++m)
                    #pragma unroll
                    for (int j = 0; j < 3; ++j)
                        acc[m][j] = MFMA16(a[m], a[j], acc[m][j]);
            }
            unsigned short* Gc = G + (size_t)c * W_N * GS;
            #pragma unroll
            for (int m = 0; m < 3; ++m)
                #pragma unroll
                for (int j = 0; j < 3; ++j)
                    #pragma unroll
                    for (int r = 0; r < 4; ++r)
                        Gc[(16 * m + 4 * q + r) * GS + 16 * j + li] =
                            f32_to_bf16(acc[m][j][r]);
            if (l < 48) {
                uint4 z = make_uint4(0u, 0u, 0u, 0u);
                *(uint4*)(Gc + l * GS + 48) = z;
                *(uint4*)(Gc + l * GS + 56) = z;
            }
        }
    } else {
        int row = (bid - 216) * 256 + t;
        if (row < I_N * R_N) {
            const float4* p = (const float4*)(images + (size_t)row * D_N);
            float s = 0.f;
            #pragma unroll 8
            for (int k = 0; k < D_N / 4; ++k) { float4 v = p[k]; s += dot4f(v, v); }
            n1sq[row] = s;
        }
    }
}

// ---- main: (caption, 4-image tile), 3 waves, coalesced packed-frag loads ----
__global__ __launch_bounds__(192) void xattn_main(
    const unsigned short* __restrict__ img_p, const unsigned short* __restrict__ rec_p,
    const unsigned short* __restrict__ G, const int* __restrict__ cap_lens,
    const float* __restrict__ n1sq, float* __restrict__ scores)
{
    __shared__ __align__(16) unsigned short awL[NCOL * AWS];  // 20736 B
    __shared__ float rs[NCOL];

    const int t = threadIdx.x;
    const int wv = t >> 6;
    const int l = t & 63;
    const int li = l & 15, q = l >> 4;
    const int c = blockIdx.x % C_N;
    const int T = blockIdx.x / C_N;        // image tile (4 images)
    const int L = cap_lens[c];
    const int n0 = wv * 48;

    // zero the K-pad region awL[:, 48:64)
    for (int k = t; k < NCOL * 4; k += 192) {
        int row = k >> 2, s = k & 3;
        *(uint2*)(awL + row * AWS + 48 + s * 4) = make_uint2(0u, 0u);
    }

    // ---- Phase 1: raw[w][n] via MFMA, fully-coalesced packed frag loads ----
    const unsigned short* pA = rec_p + (size_t)c * 24 * 512 + l * 8;
    const unsigned short* pB = img_p + ((size_t)T * 72 + wv * 24) * 512 + l * 8;
    f32x4 acc[3][3];
    #pragma unroll
    for (int m = 0; m < 3; ++m)
        #pragma unroll
        for (int j = 0; j < 3; ++j) acc[m][j] = (f32x4){0.f, 0.f, 0.f, 0.f};
    #pragma unroll
    for (int ks = 0; ks < 8; ++ks) {
        short8 a[3], b[3];
        #pragma unroll
        for (int m = 0; m < 3; ++m) a[m] = *(const short8*)(pA + (m * 8 + ks) * 512);
        #pragma unroll
        for (int j = 0; j < 3; ++j) b[j] = *(const short8*)(pB + (j * 8 + ks) * 512);
        #pragma unroll
        for (int m = 0; m < 3; ++m)
            #pragma unroll
            for (int j = 0; j < 3; ++j)
                acc[m][j] = MFMA16(a[m], b[j], acc[m][j]);
    }

    // ---- Phase 2: per-column leaky/norm/softmax in C-frag layout ----
    f32x4 aw[3][3];
    float numc[3];
    #pragma unroll
    for (int j = 0; j < 3; ++j) {
        float tmp[3][4];
        float ssq = 0.f;
        #pragma unroll
        for (int m = 0; m < 3; ++m)
            #pragma unroll
            for (int r = 0; r < 4; ++r) {
                int w = 16 * m + 4 * q + r;
                float x = acc[m][j][r];
                float lv = (x > 0.f) ? x : 0.1f * x;
                lv = (w < L) ? lv : 0.f;
                tmp[m][r] = lv;
                ssq += lv * lv;
            }
        ssq += __shfl_xor(ssq, 16); ssq += __shfl_xor(ssq, 32);
        float inv = LAM_SM / fmaxf(sqrtf(ssq), 1e-12f);
        float mx = -1e30f;
        #pragma unroll
        for (int m = 0; m < 3; ++m)
            #pragma unroll
            for (int r = 0; r < 4; ++r) {
                int w = 16 * m + 4 * q + r;
                float vv = (w < L) ? tmp[m][r] * inv : -1e30f;
                tmp[m][r] = vv;
                mx = fmaxf(mx, vv);
            }
        mx = fmaxf(mx, __shfl_xor(mx, 16)); mx = fmaxf(mx, __shfl_xor(mx, 32));
        float s = 0.f;
        #pragma unroll
        for (int m = 0; m < 3; ++m)
            #pragma unroll
            for (int r = 0; r < 4; ++r) {
                int w = 16 * m + 4 * q + r;
                float e = (w < L) ? __expf(tmp[m][r] - mx) : 0.f;
                tmp[m][r] = e;
                s += e;
            }
        s += __shfl_xor(s, 16); s += __shfl_xor(s, 32);
        float is = 1.f / s;
        float np = 0.f;
        #pragma unroll
        for (int m = 0; m < 3; ++m)
            #pragma unroll
            for (int r = 0; r < 4; ++r) {
                float a = tmp[m][r] * is;
                aw[m][j][r] = a;
                np += a * acc[m][j][r];   // raw pre-activation dot -> num
            }
        np += __shfl_xor(np, 16); np += __shfl_xor(np, 32);
        numc[j] = np;
        int n = n0 + 16 * j + li;
        #pragma unroll
        for (int m = 0; m < 3; ++m) {
            unsigned int lo = (unsigned)f32_to_bf16(aw[m][j][0]) |
                              ((unsigned)f32_to_bf16(aw[m][j][1]) << 16);
            unsigned int hi = (unsigned)f32_to_bf16(aw[m][j][2]) |
                              ((unsigned)f32_to_bf16(aw[m][j][3]) << 16);
            *(uint2*)(awL + n * AWS + 16 * m + 4 * q) = make_uint2(lo, hi);
        }
    }
    __syncthreads();

    // ---- Phase 3: H[w][n] = G . aw  (K=64 padded) ----
    #pragma unroll
    for (int m = 0; m < 3; ++m)
        #pragma unroll
        for (int j = 0; j < 3; ++j) acc[m][j] = (f32x4){0.f, 0.f, 0.f, 0.f};
    const unsigned short* pg = G + (size_t)c * W_N * GS + li * GS + 8 * q;
    #pragma unroll
    for (int ks = 0; ks < 2; ++ks) {
        short8 a[3], b[3];
        #pragma unroll
        for (int m = 0; m < 3; ++m) a[m] = *(const short8*)(pg + m * 16 * GS + 32 * ks);
        #pragma unroll
        for (int j = 0; j < 3; ++j)
            b[j] = *(const short8*)(awL + (n0 + 16 * j + li) * AWS + 32 * ks + 8 * q);
        #pragma unroll
        for (int m = 0; m < 3; ++m)
            #pragma unroll
            for (int j = 0; j < 3; ++j)
                acc[m][j] = MFMA16(a[m], b[j], acc[m][j]);
    }

    // ---- Phase 4: n2 = aw.H per column; row_sim ----
    #pragma unroll
    for (int j = 0; j < 3; ++j) {
        float n2p = 0.f;
        #pragma unroll
        for (int m = 0; m < 3; ++m)
            #pragma unroll
            for (int r = 0; r < 4; ++r)
                n2p += aw[m][j][r] * acc[m][j][r];
        n2p += __shfl_xor(n2p, 16); n2p += __shfl_xor(n2p, 32);
        if (q == 0) {
            int n = n0 + 16 * j + li;
            float n1 = n1sq[T * NCOL + n];
            float denom = fmaxf(sqrtf(n1) * sqrtf(n2p), 1e-8f);
            rs[n] = numc[j] / denom;
        }
    }
    __syncthreads();

    // ---- Phase 5: LSE over r per image ----
    if (t < 32) {
        int ii = t >> 3, k = t & 7;
        float mx = -1e30f;
        #pragma unroll
        for (int p = 0; p < 5; ++p) {
            int r = k + 8 * p;
            if (r < R_N) mx = fmaxf(mx, rs[ii * R_N + r]);
        }
        mx = fmaxf(mx, __shfl_xor(mx, 1));
        mx = fmaxf(mx, __shfl_xor(mx, 2));
        mx = fmaxf(mx, __shfl_xor(mx, 4));
        float s = 0.f;
        #pragma unroll
        for (int p = 0; p < 5; ++p) {
            int r = k + 8 * p;
            if (r < R_N) s += __expf(LAM_LSE * (rs[ii * R_N + r] - mx));
        }
        s += __shfl_xor(s, 1); s += __shfl_xor(s, 2); s += __shfl_xor(s, 4);
        if (k == 0)
            scores[(size_t)(T * NIMG + ii) * C_N + c] = (LAM_LSE * mx + __logf(s)) / LAM_LSE;
    }
}

__global__ __launch_bounds__(256) void hinge_loss_kernel(
    const float* __restrict__ S, float* __restrict__ out)
{
    __shared__ float diag[96];
    __shared__ float wsum[4];
    const int t = threadIdx.x;
    if (t < 96) diag[t] = S[t * 97];
    __syncthreads();
    float acc = 0.f;
    for (int k = t; k < 96 * 96; k += 256) {
        int ii = k / 96;
        int cc = k - ii * 96;
        if (ii != cc) {
            float s = S[k];
            acc += fmaxf(MARGIN_F + s - diag[cc], 0.f)
                 + fmaxf(MARGIN_F + s - diag[ii], 0.f);
        }
    }
    #pragma unroll
    for (int off = 32; off; off >>= 1) acc += __shfl_xor(acc, off);
    if ((t & 63) == 0) wsum[t >> 6] = acc;
    __syncthreads();
    if (t == 0) out[0] = wsum[0] + wsum[1] + wsum[2] + wsum[3];
}

extern "C" void kernel_launch(void* const* d_in, const int* in_sizes, int n_in,
                              void* d_out, int out_size, void* d_ws, size_t ws_size,
                              hipStream_t stream) {
    const float* images  = (const float*)d_in[0];
    const float* recipes = (const float*)d_in[1];
    const int*   caps    = (const int*)d_in[2];
    float* out = (float*)d_out;
    float* wsf = (float*)d_ws;
    float* scores = wsf + WSF_SCORES;
    float* n1 = wsf + WSF_N1;
    unsigned short* shb = (unsigned short*)(wsf + WSF_SHBASE);
    unsigned short* img_p = shb + SH_IMG;
    unsigned short* rec_p = shb + SH_REC;
    unsigned short* Gb    = shb + SH_G;

    hipLaunchKernelGGL(prep_all, dim3(230), dim3(256), 0, stream,
                       images, recipes, img_p, rec_p, Gb, n1);
    hipLaunchKernelGGL(xattn_main, dim3(C_N * NTILE), dim3(192), 0, stream,
                       img_p, rec_p, Gb, caps, n1, scores);
    hipLaunchKernelGGL(hinge_loss_kernel, dim3(1), dim3(256), 0, stream, scores, out);
}